// Round 2
// baseline (941.189 us; speedup 1.0000x reference)
//
#include <hip/hip_runtime.h>
#include <stdint.h>

// Problem dims (fixed)
// B=2, S=2048, D=1024, H=16, DH=64, tokens T=4096

typedef __attribute__((ext_vector_type(8))) short short8;
typedef __attribute__((ext_vector_type(4))) float f32x4;

__device__ __forceinline__ unsigned short f2b(float f) {
  union { float f; unsigned u; } v; v.f = f;
  unsigned u = v.u;
  return (unsigned short)((u + 0x7fffu + ((u >> 16) & 1u)) >> 16);
}

// ---------------- cast hidden_states fp32 -> bf16 ----------------
__global__ void k_cast_hs(const float* __restrict__ x, unsigned short* __restrict__ y, int n4) {
  int i = blockIdx.x * blockDim.x + threadIdx.x;
  if (i < n4) {
    float4 v = ((const float4*)x)[i];
    ushort4 o;
    o.x = f2b(v.x); o.y = f2b(v.y); o.z = f2b(v.z); o.w = f2b(v.w);
    ((ushort4*)y)[i] = o;
  }
}

// ---------------- transpose+cast the four weight matrices ----------------
__global__ void k_transpose_cast(const float* __restrict__ Wq, const float* __restrict__ Wk,
                                 const float* __restrict__ Wv, const float* __restrict__ Wo,
                                 unsigned short* __restrict__ Tq, unsigned short* __restrict__ Tk,
                                 unsigned short* __restrict__ Tv, unsigned short* __restrict__ To) {
  __shared__ float tile[32][33];
  const float* W; unsigned short* T;
  switch (blockIdx.z) {
    case 0: W = Wq; T = Tq; break;
    case 1: W = Wk; T = Tk; break;
    case 2: W = Wv; T = Tv; break;
    default: W = Wo; T = To; break;
  }
  int n0 = blockIdx.x * 32, k0 = blockIdx.y * 32;
  int tx = threadIdx.x, ty = threadIdx.y;
#pragma unroll
  for (int j = 0; j < 4; ++j)
    tile[ty + j * 8][tx] = W[(size_t)(k0 + ty + j * 8) * 1024 + n0 + tx];
  __syncthreads();
#pragma unroll
  for (int j = 0; j < 4; ++j)
    T[(size_t)(n0 + ty + j * 8) * 1024 + k0 + tx] = f2b(tile[tx][ty + j * 8]);
}

// ---------------- m97-style 128x128 bf16 MFMA GEMM, C = A @ Bt^T ----------------
// MODE 0: out bf16 [B,H,S,DH], rows=tokens, cols=D, +bias[col]     (Q, K)
// MODE 1: out bf16 [B,H,DH,S], rows=D (dims), cols=tokens, +bias[row]  (V transposed)
// MODE 2: out fp32 h[row*1024+col] = acc + bias[col] + resid[row*1024+col]  (out proj)
template <int MODE>
__global__ __launch_bounds__(256) void k_gemm(const unsigned short* __restrict__ A,
                                              const unsigned short* __restrict__ Bt, int Kd,
                                              const float* __restrict__ bias,
                                              const float* __restrict__ resid,
                                              void* __restrict__ outp) {
  __shared__ __align__(16) unsigned short Asm[128 * 32];
  __shared__ __align__(16) unsigned short Bsm[128 * 32];
  const int t = threadIdx.x, w = t >> 6, l = t & 63;
  const int m0 = blockIdx.y * 128, n0 = blockIdx.x * 128;
  const int wr = w >> 1, wc = w & 1;
  const int lr = l & 15, lg = l >> 4;

  f32x4 acc[4][4];
#pragma unroll
  for (int mi = 0; mi < 4; ++mi)
#pragma unroll
    for (int ni = 0; ni < 4; ++ni) acc[mi][ni] = (f32x4){0.f, 0.f, 0.f, 0.f};

  const int kcol = (l & 3) * 8;
  for (int kt = 0; kt < Kd / 32; ++kt) {
    const int k0 = kt * 32;
#pragma unroll
    for (int i = 0; i < 2; ++i) {
      int ra = (i * 4 + w) * 16 + (l >> 2);
      const unsigned short* ga = A + (size_t)(m0 + ra) * Kd + k0 + kcol;
      __builtin_amdgcn_global_load_lds((const __attribute__((address_space(1))) void*)ga,
                                       (__attribute__((address_space(3))) void*)((char*)Asm + (i * 4 + w) * 1024),
                                       16, 0, 0);
      const unsigned short* gb = Bt + (size_t)(n0 + ra) * Kd + k0 + kcol;
      __builtin_amdgcn_global_load_lds((const __attribute__((address_space(1))) void*)gb,
                                       (__attribute__((address_space(3))) void*)((char*)Bsm + (i * 4 + w) * 1024),
                                       16, 0, 0);
    }
    __syncthreads();
    short8 af[4], bfv[4];
#pragma unroll
    for (int mi = 0; mi < 4; ++mi)
      af[mi] = *(const short8*)&Asm[(wr * 64 + mi * 16 + lr) * 32 + lg * 8];
#pragma unroll
    for (int ni = 0; ni < 4; ++ni)
      bfv[ni] = *(const short8*)&Bsm[(wc * 64 + ni * 16 + lr) * 32 + lg * 8];
#pragma unroll
    for (int mi = 0; mi < 4; ++mi)
#pragma unroll
      for (int ni = 0; ni < 4; ++ni)
        acc[mi][ni] = __builtin_amdgcn_mfma_f32_16x16x32_bf16(af[mi], bfv[ni], acc[mi][ni], 0, 0, 0);
    __syncthreads();
  }

#pragma unroll
  for (int mi = 0; mi < 4; ++mi) {
#pragma unroll
    for (int ni = 0; ni < 4; ++ni) {
#pragma unroll
      for (int r = 0; r < 4; ++r) {
        int row = m0 + wr * 64 + mi * 16 + lg * 4 + r;
        int col = n0 + wc * 64 + ni * 16 + lr;
        float v = acc[mi][ni][r];
        if constexpr (MODE == 0) {
          v += bias[col];
          int b = row >> 11, s = row & 2047, h = col >> 6, dh = col & 63;
          ((unsigned short*)outp)[((size_t)((b * 16 + h) * 2048 + s)) * 64 + dh] = f2b(v);
        } else if constexpr (MODE == 1) {
          v += bias[row];
          int h = row >> 6, dh = row & 63, b = col >> 11, s = col & 2047;
          ((unsigned short*)outp)[((size_t)((b * 16 + h) * 64 + dh)) * 2048 + s] = f2b(v);
        } else {
          v += bias[col] + resid[(size_t)row * 1024 + col];
          ((float*)outp)[(size_t)row * 1024 + col] = v;
        }
      }
    }
  }
}

// ---------------- fused attention: scores + softmax + probs write + PV ----------------
// grid (S/16, H, B), block 256 (4 waves). Wave w owns score cols [w*512, w*512+512).
// probs written via LDS bounce -> fully coalesced 1KB float4 wave-stores.
__global__ __launch_bounds__(256) void k_attn(const unsigned short* __restrict__ Q,
                                              const unsigned short* __restrict__ K,
                                              const unsigned short* __restrict__ VT,
                                              const float* __restrict__ mask,
                                              float* __restrict__ probs,
                                              unsigned short* __restrict__ ctx) {
  __shared__ float smax[4][16];
  __shared__ float ssum[4][16];
  // unioned scratch: fp32 stage [16][516] (33024 B) | pbuf [4][16][264] ushort (33792 B)
  //                  | redbuf [4][16][64] f32 (16384 B)  -- used sequentially
  __shared__ __align__(16) char shbuf[34048];
  float (*stage)[516] = (float(*)[516])shbuf;
  unsigned short (*pbuf)[16][264] = (unsigned short(*)[16][264])shbuf;
  float (*redbuf)[16][64] = (float(*)[16][64])shbuf;

  const int t = threadIdx.x, w = t >> 6, l = t & 63;
  const int qb = blockIdx.x, h = blockIdx.y, b = blockIdx.z;
  const int q0 = qb * 16;
  const int lr = l & 15, lg = l >> 4;
  const size_t head = ((size_t)(b * 16 + h)) * 2048 * 64;
  const unsigned short* Qh = Q + head + (size_t)q0 * 64;
  const unsigned short* Kh = K + head;
  const unsigned short* VTh = VT + head;

  short8 aq0 = *(const short8*)(Qh + lr * 64 + lg * 8);
  short8 aq1 = *(const short8*)(Qh + lr * 64 + 32 + lg * 8);

  f32x4 sc[32];
  const float scale = 0.125f;
#pragma unroll
  for (int ni = 0; ni < 32; ++ni) {
    int col = w * 512 + ni * 16 + lr;
    short8 bk0 = *(const short8*)(Kh + (size_t)col * 64 + lg * 8);
    short8 bk1 = *(const short8*)(Kh + (size_t)col * 64 + 32 + lg * 8);
    f32x4 c = (f32x4){0.f, 0.f, 0.f, 0.f};
    c = __builtin_amdgcn_mfma_f32_16x16x32_bf16(aq0, bk0, c, 0, 0, 0);
    c = __builtin_amdgcn_mfma_f32_16x16x32_bf16(aq1, bk1, c, 0, 0, 0);
    float mval = mask[b * 2048 + col];
#pragma unroll
    for (int r = 0; r < 4; ++r) sc[ni][r] = c[r] * scale + mval;
  }

  // ---- softmax over 2048 cols per row ----
  float vmax[4] = {-1e30f, -1e30f, -1e30f, -1e30f};
#pragma unroll
  for (int ni = 0; ni < 32; ++ni)
#pragma unroll
    for (int r = 0; r < 4; ++r) vmax[r] = fmaxf(vmax[r], sc[ni][r]);
#pragma unroll
  for (int off = 8; off >= 1; off >>= 1)
#pragma unroll
    for (int r = 0; r < 4; ++r) vmax[r] = fmaxf(vmax[r], __shfl_xor(vmax[r], off));
  if (lr == 0) {
#pragma unroll
    for (int r = 0; r < 4; ++r) smax[w][lg * 4 + r] = vmax[r];
  }
  __syncthreads();
  float m[4];
#pragma unroll
  for (int r = 0; r < 4; ++r) {
    int row = lg * 4 + r;
    m[r] = fmaxf(fmaxf(smax[0][row], smax[1][row]), fmaxf(smax[2][row], smax[3][row]));
  }
  float vsum[4] = {0.f, 0.f, 0.f, 0.f};
#pragma unroll
  for (int ni = 0; ni < 32; ++ni)
#pragma unroll
    for (int r = 0; r < 4; ++r) {
      float p = __expf(sc[ni][r] - m[r]);
      sc[ni][r] = p;
      vsum[r] += p;
    }
#pragma unroll
  for (int off = 8; off >= 1; off >>= 1)
#pragma unroll
    for (int r = 0; r < 4; ++r) vsum[r] += __shfl_xor(vsum[r], off);
  if (lr == 0) {
#pragma unroll
    for (int r = 0; r < 4; ++r) ssum[w][lg * 4 + r] = vsum[r];
  }
  __syncthreads();
  float rinv[4];
#pragma unroll
  for (int r = 0; r < 4; ++r) {
    int row = lg * 4 + r;
    rinv[r] = 1.f / (ssum[0][row] + ssum[1][row] + ssum[2][row] + ssum[3][row]);
  }
#pragma unroll
  for (int ni = 0; ni < 32; ++ni)
#pragma unroll
    for (int r = 0; r < 4; ++r) sc[ni][r] *= rinv[r];

  // ---- probs write: 4 phases, LDS bounce, coalesced 1KB float4 stores ----
  const size_t prow0 = ((size_t)((b * 16 + h) * 2048 + q0)) * 2048;
#pragma unroll 1
  for (int p = 0; p < 4; ++p) {
    if (w == p) {
#pragma unroll
      for (int ni = 0; ni < 32; ++ni)
#pragma unroll
        for (int r = 0; r < 4; ++r)
          stage[lg * 4 + r][ni * 16 + lr] = sc[ni][r];
    }
    __syncthreads();
#pragma unroll
    for (int rr = 0; rr < 4; ++rr) {
      int row = w * 4 + rr;
      float4 v0 = *(const float4*)&stage[row][l * 4];
      float4 v1 = *(const float4*)&stage[row][256 + l * 4];
      float* gp = probs + prow0 + (size_t)row * 2048 + p * 512;
      ((float4*)gp)[l] = v0;
      ((float4*)(gp + 256))[l] = v1;
    }
    __syncthreads();
  }

  // ---- PV: ctx[16 x 64], K-dim split across waves (each wave its 512 cols) ----
  f32x4 cacc[4];
#pragma unroll
  for (int n = 0; n < 4; ++n) cacc[n] = (f32x4){0.f, 0.f, 0.f, 0.f};

#pragma unroll 1
  for (int chunk = 0; chunk < 2; ++chunk) {
    // write P chunk (bf16) to this wave's LDS slot (own-wave only -> no barrier needed)
#pragma unroll
    for (int ni2 = 0; ni2 < 16; ++ni2) {
      int ni = chunk * 16 + ni2;
#pragma unroll
      for (int r = 0; r < 4; ++r)
        pbuf[w][lg * 4 + r][ni2 * 16 + lr] = f2b(sc[ni][r]);
    }
#pragma unroll
    for (int kc = 0; kc < 8; ++kc) {
      short8 pa = *(const short8*)&pbuf[w][lr][kc * 32 + lg * 8];
      size_t kg = (size_t)w * 512 + chunk * 256 + kc * 32;
#pragma unroll
      for (int n = 0; n < 4; ++n) {
        short8 bv = *(const short8*)(VTh + (size_t)(n * 16 + lr) * 2048 + kg + lg * 8);
        cacc[n] = __builtin_amdgcn_mfma_f32_16x16x32_bf16(pa, bv, cacc[n], 0, 0, 0);
      }
    }
  }
  __syncthreads();  // protect redbuf (overlaps pbuf) against other waves' pbuf reads

  // cross-wave reduce of ctx partials
#pragma unroll
  for (int n = 0; n < 4; ++n)
#pragma unroll
    for (int r = 0; r < 4; ++r)
      redbuf[w][lg * 4 + r][n * 16 + lr] = cacc[n][r];
  __syncthreads();

  {
    int row = t >> 4;          // 0..15
    int c0 = (t & 15) * 4;     // 0..60
    float v0 = redbuf[0][row][c0] + redbuf[1][row][c0] + redbuf[2][row][c0] + redbuf[3][row][c0];
    float v1 = redbuf[0][row][c0 + 1] + redbuf[1][row][c0 + 1] + redbuf[2][row][c0 + 1] + redbuf[3][row][c0 + 1];
    float v2 = redbuf[0][row][c0 + 2] + redbuf[1][row][c0 + 2] + redbuf[2][row][c0 + 2] + redbuf[3][row][c0 + 2];
    float v3 = redbuf[0][row][c0 + 3] + redbuf[1][row][c0 + 3] + redbuf[2][row][c0 + 3] + redbuf[3][row][c0 + 3];
    ushort4 o;
    o.x = f2b(v0); o.y = f2b(v1); o.z = f2b(v2); o.w = f2b(v3);
    *(ushort4*)(ctx + ((size_t)(b * 2048 + q0 + row)) * 1024 + h * 64 + c0) = o;
  }
}

// ---------------- LayerNorm over D=1024 per token ----------------
__global__ __launch_bounds__(256) void k_ln(const float* __restrict__ hbuf, const float* __restrict__ g,
                                            const float* __restrict__ be, float* __restrict__ out) {
  __shared__ float psum[4];
  __shared__ float psq[4];
  int tok = blockIdx.x;
  int t = threadIdx.x, w = t >> 6;
  float4 v = ((const float4*)(hbuf + (size_t)tok * 1024))[t];
  float s = v.x + v.y + v.z + v.w;
  float q = v.x * v.x + v.y * v.y + v.z * v.z + v.w * v.w;
#pragma unroll
  for (int off = 32; off >= 1; off >>= 1) {
    s += __shfl_xor(s, off);
    q += __shfl_xor(q, off);
  }
  if ((t & 63) == 0) { psum[w] = s; psq[w] = q; }
  __syncthreads();
  float S = psum[0] + psum[1] + psum[2] + psum[3];
  float Qs = psq[0] + psq[1] + psq[2] + psq[3];
  float u = S * (1.f / 1024.f);
  float var = Qs * (1.f / 1024.f) - u * u;
  float rstd = rsqrtf(var + 1e-12f);
  float4 gv = ((const float4*)g)[t];
  float4 bv = ((const float4*)be)[t];
  float4 o;
  o.x = gv.x * ((v.x - u) * rstd) + bv.x;
  o.y = gv.y * ((v.y - u) * rstd) + bv.y;
  o.z = gv.z * ((v.z - u) * rstd) + bv.z;
  o.w = gv.w * ((v.w - u) * rstd) + bv.w;
  ((float4*)(out + (size_t)tok * 1024))[t] = o;
}

extern "C" void kernel_launch(void* const* d_in, const int* in_sizes, int n_in,
                              void* d_out, int out_size, void* d_ws, size_t ws_size,
                              hipStream_t stream) {
  const float* hs   = (const float*)d_in[0];
  const float* mask = (const float*)d_in[1];
  const float* Wq   = (const float*)d_in[2];
  const float* bq   = (const float*)d_in[3];
  const float* Wk   = (const float*)d_in[4];
  const float* bk   = (const float*)d_in[5];
  const float* Wv   = (const float*)d_in[6];
  const float* bv   = (const float*)d_in[7];
  const float* Wo   = (const float*)d_in[8];
  const float* bo   = (const float*)d_in[9];
  const float* lnw  = (const float*)d_in[10];
  const float* lnb  = (const float*)d_in[11];

  float* out = (float*)d_out;
  float* probs = out + (size_t)4194304;  // B*S*D = 2*2048*1024

  char* ws = (char*)d_ws;
  const size_t MB = 1u << 20;
  unsigned short* hsb = (unsigned short*)(ws + 0 * MB);    // 8 MB
  unsigned short* TqW = (unsigned short*)(ws + 8 * MB);    // 2 MB each
  unsigned short* TkW = (unsigned short*)(ws + 10 * MB);
  unsigned short* TvW = (unsigned short*)(ws + 12 * MB);
  unsigned short* ToW = (unsigned short*)(ws + 14 * MB);
  unsigned short* Qb  = (unsigned short*)(ws + 16 * MB);   // 8 MB
  unsigned short* Kb  = (unsigned short*)(ws + 24 * MB);   // 8 MB
  unsigned short* VTb = (unsigned short*)(ws + 32 * MB);   // 8 MB
  unsigned short* ctxb = (unsigned short*)(ws + 40 * MB);  // 8 MB
  float* hbuf = (float*)(ws + 48 * MB);                    // 16 MB

  k_cast_hs<<<4096, 256, 0, stream>>>(hs, hsb, 1048576);
  k_transpose_cast<<<dim3(32, 32, 4), dim3(32, 8), 0, stream>>>(Wq, Wk, Wv, Wo, TqW, TkW, TvW, ToW);

  // Q = hs@Wq+bq, K = hs@Wk+bk  (rows=tokens M=4096, cols=D N=1024)
  k_gemm<0><<<dim3(8, 32), 256, 0, stream>>>(hsb, TqW, 1024, bq, nullptr, Qb);
  k_gemm<0><<<dim3(8, 32), 256, 0, stream>>>(hsb, TkW, 1024, bk, nullptr, Kb);
  // VT = (hs@Wv)^T = Wv^T @ hs^T  (rows=dims M=1024, cols=tokens N=4096)
  k_gemm<1><<<dim3(32, 8), 256, 0, stream>>>(TvW, hsb, 1024, bv, nullptr, VTb);

  k_attn<<<dim3(128, 16, 2), 256, 0, stream>>>(Qb, Kb, VTb, mask, probs, ctxb);

  // h = ctx@Wo + bo + hs
  k_gemm<2><<<dim3(8, 32), 256, 0, stream>>>(ctxb, ToW, 1024, bo, hs, hbuf);
  k_ln<<<4096, 256, 0, stream>>>(hbuf, lnw, lnb, out);
}

// Round 4
// 858.821 us; speedup vs baseline: 1.0959x; 1.0959x over previous
//
#include <hip/hip_runtime.h>
#include <stdint.h>

// Problem dims (fixed)
// B=2, S=2048, D=1024, H=16, DH=64, tokens T=4096

typedef __attribute__((ext_vector_type(8))) short short8;
typedef __attribute__((ext_vector_type(4))) float f32x4;

__device__ __forceinline__ unsigned short f2b(float f) {
  union { float f; unsigned u; } v; v.f = f;
  unsigned u = v.u;
  return (unsigned short)((u + 0x7fffu + ((u >> 16) & 1u)) >> 16);
}

// ---------------- cast hidden_states fp32 -> bf16 ----------------
__global__ void k_cast_hs(const float* __restrict__ x, unsigned short* __restrict__ y, int n4) {
  int i = blockIdx.x * blockDim.x + threadIdx.x;
  if (i < n4) {
    float4 v = ((const float4*)x)[i];
    ushort4 o;
    o.x = f2b(v.x); o.y = f2b(v.y); o.z = f2b(v.z); o.w = f2b(v.w);
    ((ushort4*)y)[i] = o;
  }
}

// ---------------- transpose+cast the four weight matrices ----------------
__global__ void k_transpose_cast(const float* __restrict__ Wq, const float* __restrict__ Wk,
                                 const float* __restrict__ Wv, const float* __restrict__ Wo,
                                 unsigned short* __restrict__ Tq, unsigned short* __restrict__ Tk,
                                 unsigned short* __restrict__ Tv, unsigned short* __restrict__ To) {
  __shared__ float tile[32][33];
  const float* W; unsigned short* T;
  switch (blockIdx.z) {
    case 0: W = Wq; T = Tq; break;
    case 1: W = Wk; T = Tk; break;
    case 2: W = Wv; T = Tv; break;
    default: W = Wo; T = To; break;
  }
  int n0 = blockIdx.x * 32, k0 = blockIdx.y * 32;
  int tx = threadIdx.x, ty = threadIdx.y;
#pragma unroll
  for (int j = 0; j < 4; ++j)
    tile[ty + j * 8][tx] = W[(size_t)(k0 + ty + j * 8) * 1024 + n0 + tx];
  __syncthreads();
#pragma unroll
  for (int j = 0; j < 4; ++j)
    T[(size_t)(n0 + ty + j * 8) * 1024 + k0 + tx] = f2b(tile[tx][ty + j * 8]);
}

// ---------------- m97-style 128x128 bf16 MFMA GEMM, C = A @ Bt^T ----------------
// MODE 0: out bf16 [B,H,S,DH], rows=tokens, cols=D, v=(acc+bias[col])*qscale  (Q, K)
// MODE 1: out bf16 [B,H,DH,S], rows=D (dims), cols=tokens, +bias[row]  (V transposed)
// MODE 2: out fp32 h[row*1024+col] = acc + bias[col] + resid[row*1024+col]  (out proj)
template <int MODE>
__global__ __launch_bounds__(256) void k_gemm(const unsigned short* __restrict__ A,
                                              const unsigned short* __restrict__ Bt, int Kd,
                                              const float* __restrict__ bias,
                                              const float* __restrict__ resid,
                                              void* __restrict__ outp, float qscale) {
  __shared__ __align__(16) unsigned short Asm[128 * 32];
  __shared__ __align__(16) unsigned short Bsm[128 * 32];
  const int t = threadIdx.x, w = t >> 6, l = t & 63;
  const int m0 = blockIdx.y * 128, n0 = blockIdx.x * 128;
  const int wr = w >> 1, wc = w & 1;
  const int lr = l & 15, lg = l >> 4;

  f32x4 acc[4][4];
#pragma unroll
  for (int mi = 0; mi < 4; ++mi)
#pragma unroll
    for (int ni = 0; ni < 4; ++ni) acc[mi][ni] = (f32x4){0.f, 0.f, 0.f, 0.f};

  const int kcol = (l & 3) * 8;
  for (int kt = 0; kt < Kd / 32; ++kt) {
    const int k0 = kt * 32;
#pragma unroll
    for (int i = 0; i < 2; ++i) {
      int ra = (i * 4 + w) * 16 + (l >> 2);
      const unsigned short* ga = A + (size_t)(m0 + ra) * Kd + k0 + kcol;
      __builtin_amdgcn_global_load_lds((const __attribute__((address_space(1))) void*)ga,
                                       (__attribute__((address_space(3))) void*)((char*)Asm + (i * 4 + w) * 1024),
                                       16, 0, 0);
      const unsigned short* gb = Bt + (size_t)(n0 + ra) * Kd + k0 + kcol;
      __builtin_amdgcn_global_load_lds((const __attribute__((address_space(1))) void*)gb,
                                       (__attribute__((address_space(3))) void*)((char*)Bsm + (i * 4 + w) * 1024),
                                       16, 0, 0);
    }
    __syncthreads();
    short8 af[4], bfv[4];
#pragma unroll
    for (int mi = 0; mi < 4; ++mi)
      af[mi] = *(const short8*)&Asm[(wr * 64 + mi * 16 + lr) * 32 + lg * 8];
#pragma unroll
    for (int ni = 0; ni < 4; ++ni)
      bfv[ni] = *(const short8*)&Bsm[(wc * 64 + ni * 16 + lr) * 32 + lg * 8];
#pragma unroll
    for (int mi = 0; mi < 4; ++mi)
#pragma unroll
      for (int ni = 0; ni < 4; ++ni)
        acc[mi][ni] = __builtin_amdgcn_mfma_f32_16x16x32_bf16(af[mi], bfv[ni], acc[mi][ni], 0, 0, 0);
    __syncthreads();
  }

#pragma unroll
  for (int mi = 0; mi < 4; ++mi) {
#pragma unroll
    for (int ni = 0; ni < 4; ++ni) {
#pragma unroll
      for (int r = 0; r < 4; ++r) {
        int row = m0 + wr * 64 + mi * 16 + lg * 4 + r;
        int col = n0 + wc * 64 + ni * 16 + lr;
        float v = acc[mi][ni][r];
        if constexpr (MODE == 0) {
          v = (v + bias[col]) * qscale;
          int b = row >> 11, s = row & 2047, h = col >> 6, dh = col & 63;
          ((unsigned short*)outp)[((size_t)((b * 16 + h) * 2048 + s)) * 64 + dh] = f2b(v);
        } else if constexpr (MODE == 1) {
          v += bias[row];
          int h = row >> 6, dh = row & 63, b = col >> 11, s = col & 2047;
          ((unsigned short*)outp)[((size_t)((b * 16 + h) * 64 + dh)) * 2048 + s] = f2b(v);
        } else {
          v += bias[col] + resid[(size_t)row * 1024 + col];
          ((float*)outp)[(size_t)row * 1024 + col] = v;
        }
      }
    }
  }
}

// ---------------- fused attention: scores + softmax + probs write + PV ----------------
// grid (S/16, H, B), block 256 (4 waves). Wave w owns score cols [w*512, w*512+512).
// SWAPPED QK^T: mfma(K,Q) -> lane holds one q-row (q = lane&15), k in regs.
// probs stores are per-lane float4, row-major contiguous. No LDS bounce.
__global__ __launch_bounds__(256, 2) void k_attn(const unsigned short* __restrict__ Q,
                                                 const unsigned short* __restrict__ K,
                                                 const unsigned short* __restrict__ VT,
                                                 const float* __restrict__ mask,
                                                 float* __restrict__ probs,
                                                 unsigned short* __restrict__ ctx) {
  __shared__ float smax[4][16];
  __shared__ float ssum[4][16];
  // unioned scratch: pbuf [4][16][264] ushort (33792 B) | redbuf [4][16][64] f32 (16384 B)
  __shared__ __align__(16) char shbuf[33792];
  unsigned short (*pbuf)[16][264] = (unsigned short(*)[16][264])shbuf;
  float (*redbuf)[16][64] = (float(*)[16][64])shbuf;

  const int t = threadIdx.x, w = t >> 6, l = t & 63;
  const int qb = blockIdx.x, h = blockIdx.y, b = blockIdx.z;
  const int q0 = qb * 16;
  const int lr = l & 15, lg = l >> 4;
  const size_t head = ((size_t)(b * 16 + h)) * 2048 * 64;
  const unsigned short* Qh = Q + head + (size_t)q0 * 64;
  const unsigned short* Kh = K + head;
  const unsigned short* VTh = VT + head;

  // Q fragment as B-operand: col=lr -> q row, k = lg*8+j
  short8 aq0 = *(const short8*)(Qh + lr * 64 + lg * 8);
  short8 aq1 = *(const short8*)(Qh + lr * 64 + 32 + lg * 8);

  f32x4 sc[32];
#pragma unroll
  for (int ni = 0; ni < 32; ++ni) {
    int col = w * 512 + ni * 16 + lr;  // K row (A-operand row index)
    short8 bk0 = *(const short8*)(Kh + (size_t)col * 64 + lg * 8);
    short8 bk1 = *(const short8*)(Kh + (size_t)col * 64 + 32 + lg * 8);
    f32x4 c = (f32x4){0.f, 0.f, 0.f, 0.f};
    c = __builtin_amdgcn_mfma_f32_16x16x32_bf16(bk0, aq0, c, 0, 0, 0);  // A=K, B=Q
    c = __builtin_amdgcn_mfma_f32_16x16x32_bf16(bk1, aq1, c, 0, 0, 0);
    // lane holds S[k = w*512+ni*16+lg*4+r][q = lr]; scale already folded into Q
    f32x4 mv = *(const f32x4*)(mask + b * 2048 + w * 512 + ni * 16 + lg * 4);
    sc[ni] = c + mv;
  }

  // ---- softmax: row q=lr is lane-local; k spread over regs + lg groups ----
  float vmax = -1e30f;
#pragma unroll
  for (int ni = 0; ni < 32; ++ni)
#pragma unroll
    for (int r = 0; r < 4; ++r) vmax = fmaxf(vmax, sc[ni][r]);
  vmax = fmaxf(vmax, __shfl_xor(vmax, 16));
  vmax = fmaxf(vmax, __shfl_xor(vmax, 32));
  if (l < 16) smax[w][l] = vmax;
  __syncthreads();
  float m = fmaxf(fmaxf(smax[0][lr], smax[1][lr]), fmaxf(smax[2][lr], smax[3][lr]));

  float vsum = 0.f;
#pragma unroll
  for (int ni = 0; ni < 32; ++ni)
#pragma unroll
    for (int r = 0; r < 4; ++r) {
      float p = __expf(sc[ni][r] - m);
      sc[ni][r] = p;
      vsum += p;
    }
  vsum += __shfl_xor(vsum, 16);
  vsum += __shfl_xor(vsum, 32);
  if (l < 16) ssum[w][l] = vsum;
  __syncthreads();
  float rinv = 1.f / (ssum[0][lr] + ssum[1][lr] + ssum[2][lr] + ssum[3][lr]);

#pragma unroll
  for (int ni = 0; ni < 32; ++ni) sc[ni] *= rinv;

  // ---- probs store: per-lane float4, row-major contiguous ----
  {
    float* prow = probs + ((size_t)((b * 16 + h) * 2048 + q0 + lr)) * 2048 + w * 512 + lg * 4;
#pragma unroll
    for (int ni = 0; ni < 32; ++ni)
      *(f32x4*)(prow + ni * 16) = sc[ni];
  }

  // ---- PV: ctx[16 x 64], K-dim split across waves (each wave its 512 cols) ----
  f32x4 cacc[4];
#pragma unroll
  for (int n = 0; n < 4; ++n) cacc[n] = (f32x4){0.f, 0.f, 0.f, 0.f};

#pragma unroll 1
  for (int chunk = 0; chunk < 2; ++chunk) {
    // P chunk -> own-wave LDS slot: pbuf[w][q=lr][k_local], packed ushort4
#pragma unroll
    for (int ni2 = 0; ni2 < 16; ++ni2) {
      int ni = chunk * 16 + ni2;
      ushort4 pk;
      pk.x = f2b(sc[ni][0]); pk.y = f2b(sc[ni][1]);
      pk.z = f2b(sc[ni][2]); pk.w = f2b(sc[ni][3]);
      *(ushort4*)&pbuf[w][lr][ni2 * 16 + lg * 4] = pk;
    }
#pragma unroll
    for (int kc = 0; kc < 8; ++kc) {
      short8 pa = *(const short8*)&pbuf[w][lr][kc * 32 + lg * 8];
      size_t kg = (size_t)w * 512 + chunk * 256 + kc * 32;
#pragma unroll
      for (int n = 0; n < 4; ++n) {
        short8 bv = *(const short8*)(VTh + (size_t)(n * 16 + lr) * 2048 + kg + lg * 8);
        cacc[n] = __builtin_amdgcn_mfma_f32_16x16x32_bf16(pa, bv, cacc[n], 0, 0, 0);
      }
    }
  }
  __syncthreads();  // protect redbuf (overlaps pbuf)

  // cross-wave reduce of ctx partials
#pragma unroll
  for (int n = 0; n < 4; ++n)
#pragma unroll
    for (int r = 0; r < 4; ++r)
      redbuf[w][lg * 4 + r][n * 16 + lr] = cacc[n][r];
  __syncthreads();

  {
    int row = t >> 4;          // 0..15
    int c0 = (t & 15) * 4;     // 0..60
    float v0 = redbuf[0][row][c0] + redbuf[1][row][c0] + redbuf[2][row][c0] + redbuf[3][row][c0];
    float v1 = redbuf[0][row][c0 + 1] + redbuf[1][row][c0 + 1] + redbuf[2][row][c0 + 1] + redbuf[3][row][c0 + 1];
    float v2 = redbuf[0][row][c0 + 2] + redbuf[1][row][c0 + 2] + redbuf[2][row][c0 + 2] + redbuf[3][row][c0 + 2];
    float v3 = redbuf[0][row][c0 + 3] + redbuf[1][row][c0 + 3] + redbuf[2][row][c0 + 3] + redbuf[3][row][c0 + 3];
    ushort4 o;
    o.x = f2b(v0); o.y = f2b(v1); o.z = f2b(v2); o.w = f2b(v3);
    *(ushort4*)(ctx + ((size_t)(b * 2048 + q0 + row)) * 1024 + h * 64 + c0) = o;
  }
}

// ---------------- LayerNorm over D=1024 per token ----------------
__global__ __launch_bounds__(256) void k_ln(const float* __restrict__ hbuf, const float* __restrict__ g,
                                            const float* __restrict__ be, float* __restrict__ out) {
  __shared__ float psum[4];
  __shared__ float psq[4];
  int tok = blockIdx.x;
  int t = threadIdx.x, w = t >> 6;
  float4 v = ((const float4*)(hbuf + (size_t)tok * 1024))[t];
  float s = v.x + v.y + v.z + v.w;
  float q = v.x * v.x + v.y * v.y + v.z * v.z + v.w * v.w;
#pragma unroll
  for (int off = 32; off >= 1; off >>= 1) {
    s += __shfl_xor(s, off);
    q += __shfl_xor(q, off);
  }
  if ((t & 63) == 0) { psum[w] = s; psq[w] = q; }
  __syncthreads();
  float S = psum[0] + psum[1] + psum[2] + psum[3];
  float Qs = psq[0] + psq[1] + psq[2] + psq[3];
  float u = S * (1.f / 1024.f);
  float var = Qs * (1.f / 1024.f) - u * u;
  float rstd = rsqrtf(var + 1e-12f);
  float4 gv = ((const float4*)g)[t];
  float4 bv = ((const float4*)be)[t];
  float4 o;
  o.x = gv.x * ((v.x - u) * rstd) + bv.x;
  o.y = gv.y * ((v.y - u) * rstd) + bv.y;
  o.z = gv.z * ((v.z - u) * rstd) + bv.z;
  o.w = gv.w * ((v.w - u) * rstd) + bv.w;
  ((float4*)(out + (size_t)tok * 1024))[t] = o;
}

extern "C" void kernel_launch(void* const* d_in, const int* in_sizes, int n_in,
                              void* d_out, int out_size, void* d_ws, size_t ws_size,
                              hipStream_t stream) {
  const float* hs   = (const float*)d_in[0];
  const float* mask = (const float*)d_in[1];
  const float* Wq   = (const float*)d_in[2];
  const float* bq   = (const float*)d_in[3];
  const float* Wk   = (const float*)d_in[4];
  const float* bk   = (const float*)d_in[5];
  const float* Wv   = (const float*)d_in[6];
  const float* bv   = (const float*)d_in[7];
  const float* Wo   = (const float*)d_in[8];
  const float* bo   = (const float*)d_in[9];
  const float* lnw  = (const float*)d_in[10];
  const float* lnb  = (const float*)d_in[11];

  float* out = (float*)d_out;
  float* probs = out + (size_t)4194304;  // B*S*D = 2*2048*1024

  char* ws = (char*)d_ws;
  const size_t MB = 1u << 20;
  unsigned short* hsb = (unsigned short*)(ws + 0 * MB);    // 8 MB
  unsigned short* TqW = (unsigned short*)(ws + 8 * MB);    // 2 MB each
  unsigned short* TkW = (unsigned short*)(ws + 10 * MB);
  unsigned short* TvW = (unsigned short*)(ws + 12 * MB);
  unsigned short* ToW = (unsigned short*)(ws + 14 * MB);
  unsigned short* Qb  = (unsigned short*)(ws + 16 * MB);   // 8 MB
  unsigned short* Kb  = (unsigned short*)(ws + 24 * MB);   // 8 MB
  unsigned short* VTb = (unsigned short*)(ws + 32 * MB);   // 8 MB
  unsigned short* ctxb = (unsigned short*)(ws + 40 * MB);  // 8 MB
  float* hbuf = (float*)(ws + 48 * MB);                    // 16 MB

  k_cast_hs<<<4096, 256, 0, stream>>>(hs, hsb, 1048576);
  k_transpose_cast<<<dim3(32, 32, 4), dim3(32, 8), 0, stream>>>(Wq, Wk, Wv, Wo, TqW, TkW, TvW, ToW);

  // Q = (hs@Wq+bq)*0.125, K = hs@Wk+bk  (rows=tokens M=4096, cols=D N=1024)
  k_gemm<0><<<dim3(8, 32), 256, 0, stream>>>(hsb, TqW, 1024, bq, nullptr, Qb, 0.125f);
  k_gemm<0><<<dim3(8, 32), 256, 0, stream>>>(hsb, TkW, 1024, bk, nullptr, Kb, 1.0f);
  // VT = (hs@Wv)^T = Wv^T @ hs^T  (rows=dims M=1024, cols=tokens N=4096)
  k_gemm<1><<<dim3(32, 8), 256, 0, stream>>>(TvW, hsb, 1024, bv, nullptr, VTb, 1.0f);

  k_attn<<<dim3(128, 16, 2), 256, 0, stream>>>(Qb, Kb, VTb, mask, probs, ctxb);

  // h = ctx@Wo + bo + hs
  k_gemm<2><<<dim3(8, 32), 256, 0, stream>>>(ctxb, ToW, 1024, bo, hs, hbuf, 1.0f);
  k_ln<<<4096, 256, 0, stream>>>(hbuf, lnw, lnb, out);
}

// Round 5
// 559.613 us; speedup vs baseline: 1.6819x; 1.5347x over previous
//
#include <hip/hip_runtime.h>
#include <stdint.h>

// Problem dims (fixed)
// B=2, S=2048, D=1024, H=16, DH=64, tokens T=4096

typedef __attribute__((ext_vector_type(8))) short short8;
typedef __attribute__((ext_vector_type(4))) float f32x4;

__device__ __forceinline__ unsigned short f2b(float f) {
  union { float f; unsigned u; } v; v.f = f;
  unsigned u = v.u;
  return (unsigned short)((u + 0x7fffu + ((u >> 16) & 1u)) >> 16);
}

// ---------------- cast hidden_states fp32 -> bf16 ----------------
__global__ void k_cast_hs(const float* __restrict__ x, unsigned short* __restrict__ y, int n4) {
  int i = blockIdx.x * blockDim.x + threadIdx.x;
  if (i < n4) {
    float4 v = ((const float4*)x)[i];
    ushort4 o;
    o.x = f2b(v.x); o.y = f2b(v.y); o.z = f2b(v.z); o.w = f2b(v.w);
    ((ushort4*)y)[i] = o;
  }
}

// ---------------- transpose+cast the four weight matrices ----------------
__global__ void k_transpose_cast(const float* __restrict__ Wq, const float* __restrict__ Wk,
                                 const float* __restrict__ Wv, const float* __restrict__ Wo,
                                 unsigned short* __restrict__ Tq, unsigned short* __restrict__ Tk,
                                 unsigned short* __restrict__ Tv, unsigned short* __restrict__ To) {
  __shared__ float tile[32][33];
  const float* W; unsigned short* T;
  switch (blockIdx.z) {
    case 0: W = Wq; T = Tq; break;
    case 1: W = Wk; T = Tk; break;
    case 2: W = Wv; T = Tv; break;
    default: W = Wo; T = To; break;
  }
  int n0 = blockIdx.x * 32, k0 = blockIdx.y * 32;
  int tx = threadIdx.x, ty = threadIdx.y;
#pragma unroll
  for (int j = 0; j < 4; ++j)
    tile[ty + j * 8][tx] = W[(size_t)(k0 + ty + j * 8) * 1024 + n0 + tx];
  __syncthreads();
#pragma unroll
  for (int j = 0; j < 4; ++j)
    T[(size_t)(n0 + ty + j * 8) * 1024 + k0 + tx] = f2b(tile[tx][ty + j * 8]);
}

// ---------------- m97-style 128x128 bf16 MFMA GEMM, C = A @ Bt^T ----------------
// MODE 0: out bf16 [B,H,S,DH], rows=tokens, cols=D, v=(acc+bias[col])*qscale  (Q, K)
// MODE 1: out bf16 [B,H,DH,S], rows=D (dims), cols=tokens, +bias[row]  (V transposed)
// MODE 2: out fp32 h[row*1024+col] = acc + bias[col] + resid[row*1024+col]  (out proj)
template <int MODE>
__global__ __launch_bounds__(256) void k_gemm(const unsigned short* __restrict__ A,
                                              const unsigned short* __restrict__ Bt, int Kd,
                                              const float* __restrict__ bias,
                                              const float* __restrict__ resid,
                                              void* __restrict__ outp, float qscale) {
  __shared__ __align__(16) unsigned short Asm[128 * 32];
  __shared__ __align__(16) unsigned short Bsm[128 * 32];
  const int t = threadIdx.x, w = t >> 6, l = t & 63;
  const int m0 = blockIdx.y * 128, n0 = blockIdx.x * 128;
  const int wr = w >> 1, wc = w & 1;
  const int lr = l & 15, lg = l >> 4;

  f32x4 acc[4][4];
#pragma unroll
  for (int mi = 0; mi < 4; ++mi)
#pragma unroll
    for (int ni = 0; ni < 4; ++ni) acc[mi][ni] = (f32x4){0.f, 0.f, 0.f, 0.f};

  const int kcol = (l & 3) * 8;
  for (int kt = 0; kt < Kd / 32; ++kt) {
    const int k0 = kt * 32;
#pragma unroll
    for (int i = 0; i < 2; ++i) {
      int ra = (i * 4 + w) * 16 + (l >> 2);
      const unsigned short* ga = A + (size_t)(m0 + ra) * Kd + k0 + kcol;
      __builtin_amdgcn_global_load_lds((const __attribute__((address_space(1))) void*)ga,
                                       (__attribute__((address_space(3))) void*)((char*)Asm + (i * 4 + w) * 1024),
                                       16, 0, 0);
      const unsigned short* gb = Bt + (size_t)(n0 + ra) * Kd + k0 + kcol;
      __builtin_amdgcn_global_load_lds((const __attribute__((address_space(1))) void*)gb,
                                       (__attribute__((address_space(3))) void*)((char*)Bsm + (i * 4 + w) * 1024),
                                       16, 0, 0);
    }
    __syncthreads();
    short8 af[4], bfv[4];
#pragma unroll
    for (int mi = 0; mi < 4; ++mi)
      af[mi] = *(const short8*)&Asm[(wr * 64 + mi * 16 + lr) * 32 + lg * 8];
#pragma unroll
    for (int ni = 0; ni < 4; ++ni)
      bfv[ni] = *(const short8*)&Bsm[(wc * 64 + ni * 16 + lr) * 32 + lg * 8];
#pragma unroll
    for (int mi = 0; mi < 4; ++mi)
#pragma unroll
      for (int ni = 0; ni < 4; ++ni)
        acc[mi][ni] = __builtin_amdgcn_mfma_f32_16x16x32_bf16(af[mi], bfv[ni], acc[mi][ni], 0, 0, 0);
    __syncthreads();
  }

#pragma unroll
  for (int mi = 0; mi < 4; ++mi) {
#pragma unroll
    for (int ni = 0; ni < 4; ++ni) {
#pragma unroll
      for (int r = 0; r < 4; ++r) {
        int row = m0 + wr * 64 + mi * 16 + lg * 4 + r;
        int col = n0 + wc * 64 + ni * 16 + lr;
        float v = acc[mi][ni][r];
        if constexpr (MODE == 0) {
          v = (v + bias[col]) * qscale;
          int b = row >> 11, s = row & 2047, h = col >> 6, dh = col & 63;
          ((unsigned short*)outp)[((size_t)((b * 16 + h) * 2048 + s)) * 64 + dh] = f2b(v);
        } else if constexpr (MODE == 1) {
          v += bias[row];
          int h = row >> 6, dh = row & 63, b = col >> 11, s = col & 2047;
          ((unsigned short*)outp)[((size_t)((b * 16 + h) * 64 + dh)) * 2048 + s] = f2b(v);
        } else {
          v += bias[col] + resid[(size_t)row * 1024 + col];
          ((float*)outp)[(size_t)row * 1024 + col] = v;
        }
      }
    }
  }
}

// ---------------- fused attention: scores + softmax + probs write + PV ----------------
// grid (S/16, H, B), block 256 (4 waves). Wave w owns score cols [w*512, w*512+512).
// SWAPPED QK^T: mfma(K,Q) -> lane holds one q-row (q = lane&15), k in regs.
// probs stores are per-lane float4, row-major contiguous. No LDS bounce.
// NOTE: every loop touching sc[] MUST be fully unrolled (rule #20: runtime
// indexing demotes the whole array to scratch -> 1.5 GB spill traffic).
__global__ __launch_bounds__(256, 2) void k_attn(const unsigned short* __restrict__ Q,
                                                 const unsigned short* __restrict__ K,
                                                 const unsigned short* __restrict__ VT,
                                                 const float* __restrict__ mask,
                                                 float* __restrict__ probs,
                                                 unsigned short* __restrict__ ctx) {
  __shared__ float smax[4][16];
  __shared__ float ssum[4][16];
  // unioned scratch: pbuf [4][16][264] ushort (33792 B) | redbuf [4][16][64] f32 (16384 B)
  __shared__ __align__(16) char shbuf[33792];
  unsigned short (*pbuf)[16][264] = (unsigned short(*)[16][264])shbuf;
  float (*redbuf)[16][64] = (float(*)[16][64])shbuf;

  const int t = threadIdx.x, w = t >> 6, l = t & 63;
  const int qb = blockIdx.x, h = blockIdx.y, b = blockIdx.z;
  const int q0 = qb * 16;
  const int lr = l & 15, lg = l >> 4;
  const size_t head = ((size_t)(b * 16 + h)) * 2048 * 64;
  const unsigned short* Qh = Q + head + (size_t)q0 * 64;
  const unsigned short* Kh = K + head;
  const unsigned short* VTh = VT + head;

  // Q fragment as B-operand: col=lr -> q row, k = lg*8+j
  short8 aq0 = *(const short8*)(Qh + lr * 64 + lg * 8);
  short8 aq1 = *(const short8*)(Qh + lr * 64 + 32 + lg * 8);

  f32x4 sc[32];
#pragma unroll
  for (int ni = 0; ni < 32; ++ni) {
    int col = w * 512 + ni * 16 + lr;  // K row (A-operand row index)
    short8 bk0 = *(const short8*)(Kh + (size_t)col * 64 + lg * 8);
    short8 bk1 = *(const short8*)(Kh + (size_t)col * 64 + 32 + lg * 8);
    f32x4 c = (f32x4){0.f, 0.f, 0.f, 0.f};
    c = __builtin_amdgcn_mfma_f32_16x16x32_bf16(bk0, aq0, c, 0, 0, 0);  // A=K, B=Q
    c = __builtin_amdgcn_mfma_f32_16x16x32_bf16(bk1, aq1, c, 0, 0, 0);
    // lane holds S[k = w*512+ni*16+lg*4+r][q = lr]; scale already folded into Q
    f32x4 mv = *(const f32x4*)(mask + b * 2048 + w * 512 + ni * 16 + lg * 4);
    sc[ni] = c + mv;
  }

  // ---- softmax: row q=lr is lane-local; k spread over regs + lg groups ----
  float vmax = -1e30f;
#pragma unroll
  for (int ni = 0; ni < 32; ++ni)
#pragma unroll
    for (int r = 0; r < 4; ++r) vmax = fmaxf(vmax, sc[ni][r]);
  vmax = fmaxf(vmax, __shfl_xor(vmax, 16));
  vmax = fmaxf(vmax, __shfl_xor(vmax, 32));
  if (l < 16) smax[w][l] = vmax;
  __syncthreads();
  float m = fmaxf(fmaxf(smax[0][lr], smax[1][lr]), fmaxf(smax[2][lr], smax[3][lr]));

  float vsum = 0.f;
#pragma unroll
  for (int ni = 0; ni < 32; ++ni)
#pragma unroll
    for (int r = 0; r < 4; ++r) {
      float p = __expf(sc[ni][r] - m);
      sc[ni][r] = p;
      vsum += p;
    }
  vsum += __shfl_xor(vsum, 16);
  vsum += __shfl_xor(vsum, 32);
  if (l < 16) ssum[w][l] = vsum;
  __syncthreads();
  float rinv = 1.f / (ssum[0][lr] + ssum[1][lr] + ssum[2][lr] + ssum[3][lr]);

#pragma unroll
  for (int ni = 0; ni < 32; ++ni) sc[ni] *= rinv;

  // ---- probs store: per-lane float4, row-major contiguous ----
  {
    float* prow = probs + ((size_t)((b * 16 + h) * 2048 + q0 + lr)) * 2048 + w * 512 + lg * 4;
#pragma unroll
    for (int ni = 0; ni < 32; ++ni)
      *(f32x4*)(prow + ni * 16) = sc[ni];
  }

  // ---- PV: ctx[16 x 64], K-dim split across waves (each wave its 512 cols) ----
  f32x4 cacc[4];
#pragma unroll
  for (int n = 0; n < 4; ++n) cacc[n] = (f32x4){0.f, 0.f, 0.f, 0.f};

#pragma unroll
  for (int chunk = 0; chunk < 2; ++chunk) {
    // P chunk -> own-wave LDS slot: pbuf[w][q=lr][k_local], packed ushort4
#pragma unroll
    for (int ni2 = 0; ni2 < 16; ++ni2) {
      int ni = chunk * 16 + ni2;
      ushort4 pk;
      pk.x = f2b(sc[ni][0]); pk.y = f2b(sc[ni][1]);
      pk.z = f2b(sc[ni][2]); pk.w = f2b(sc[ni][3]);
      *(ushort4*)&pbuf[w][lr][ni2 * 16 + lg * 4] = pk;
    }
#pragma unroll
    for (int kc = 0; kc < 8; ++kc) {
      short8 pa = *(const short8*)&pbuf[w][lr][kc * 32 + lg * 8];
      size_t kg = (size_t)w * 512 + chunk * 256 + kc * 32;
#pragma unroll
      for (int n = 0; n < 4; ++n) {
        short8 bv = *(const short8*)(VTh + (size_t)(n * 16 + lr) * 2048 + kg + lg * 8);
        cacc[n] = __builtin_amdgcn_mfma_f32_16x16x32_bf16(pa, bv, cacc[n], 0, 0, 0);
      }
    }
  }
  __syncthreads();  // protect redbuf (overlaps pbuf)

  // cross-wave reduce of ctx partials
#pragma unroll
  for (int n = 0; n < 4; ++n)
#pragma unroll
    for (int r = 0; r < 4; ++r)
      redbuf[w][lg * 4 + r][n * 16 + lr] = cacc[n][r];
  __syncthreads();

  {
    int row = t >> 4;          // 0..15
    int c0 = (t & 15) * 4;     // 0..60
    float v0 = redbuf[0][row][c0] + redbuf[1][row][c0] + redbuf[2][row][c0] + redbuf[3][row][c0];
    float v1 = redbuf[0][row][c0 + 1] + redbuf[1][row][c0 + 1] + redbuf[2][row][c0 + 1] + redbuf[3][row][c0 + 1];
    float v2 = redbuf[0][row][c0 + 2] + redbuf[1][row][c0 + 2] + redbuf[2][row][c0 + 2] + redbuf[3][row][c0 + 2];
    float v3 = redbuf[0][row][c0 + 3] + redbuf[1][row][c0 + 3] + redbuf[2][row][c0 + 3] + redbuf[3][row][c0 + 3];
    ushort4 o;
    o.x = f2b(v0); o.y = f2b(v1); o.z = f2b(v2); o.w = f2b(v3);
    *(ushort4*)(ctx + ((size_t)(b * 2048 + q0 + row)) * 1024 + h * 64 + c0) = o;
  }
}

// ---------------- LayerNorm over D=1024 per token ----------------
__global__ __launch_bounds__(256) void k_ln(const float* __restrict__ hbuf, const float* __restrict__ g,
                                            const float* __restrict__ be, float* __restrict__ out) {
  __shared__ float psum[4];
  __shared__ float psq[4];
  int tok = blockIdx.x;
  int t = threadIdx.x, w = t >> 6;
  float4 v = ((const float4*)(hbuf + (size_t)tok * 1024))[t];
  float s = v.x + v.y + v.z + v.w;
  float q = v.x * v.x + v.y * v.y + v.z * v.z + v.w * v.w;
#pragma unroll
  for (int off = 32; off >= 1; off >>= 1) {
    s += __shfl_xor(s, off);
    q += __shfl_xor(q, off);
  }
  if ((t & 63) == 0) { psum[w] = s; psq[w] = q; }
  __syncthreads();
  float S = psum[0] + psum[1] + psum[2] + psum[3];
  float Qs = psq[0] + psq[1] + psq[2] + psq[3];
  float u = S * (1.f / 1024.f);
  float var = Qs * (1.f / 1024.f) - u * u;
  float rstd = rsqrtf(var + 1e-12f);
  float4 gv = ((const float4*)g)[t];
  float4 bv = ((const float4*)be)[t];
  float4 o;
  o.x = gv.x * ((v.x - u) * rstd) + bv.x;
  o.y = gv.y * ((v.y - u) * rstd) + bv.y;
  o.z = gv.z * ((v.z - u) * rstd) + bv.z;
  o.w = gv.w * ((v.w - u) * rstd) + bv.w;
  ((float4*)(out + (size_t)tok * 1024))[t] = o;
}

extern "C" void kernel_launch(void* const* d_in, const int* in_sizes, int n_in,
                              void* d_out, int out_size, void* d_ws, size_t ws_size,
                              hipStream_t stream) {
  const float* hs   = (const float*)d_in[0];
  const float* mask = (const float*)d_in[1];
  const float* Wq   = (const float*)d_in[2];
  const float* bq   = (const float*)d_in[3];
  const float* Wk   = (const float*)d_in[4];
  const float* bk   = (const float*)d_in[5];
  const float* Wv   = (const float*)d_in[6];
  const float* bv   = (const float*)d_in[7];
  const float* Wo   = (const float*)d_in[8];
  const float* bo   = (const float*)d_in[9];
  const float* lnw  = (const float*)d_in[10];
  const float* lnb  = (const float*)d_in[11];

  float* out = (float*)d_out;
  float* probs = out + (size_t)4194304;  // B*S*D = 2*2048*1024

  char* ws = (char*)d_ws;
  const size_t MB = 1u << 20;
  unsigned short* hsb = (unsigned short*)(ws + 0 * MB);    // 8 MB
  unsigned short* TqW = (unsigned short*)(ws + 8 * MB);    // 2 MB each
  unsigned short* TkW = (unsigned short*)(ws + 10 * MB);
  unsigned short* TvW = (unsigned short*)(ws + 12 * MB);
  unsigned short* ToW = (unsigned short*)(ws + 14 * MB);
  unsigned short* Qb  = (unsigned short*)(ws + 16 * MB);   // 8 MB
  unsigned short* Kb  = (unsigned short*)(ws + 24 * MB);   // 8 MB
  unsigned short* VTb = (unsigned short*)(ws + 32 * MB);   // 8 MB
  unsigned short* ctxb = (unsigned short*)(ws + 40 * MB);  // 8 MB
  float* hbuf = (float*)(ws + 48 * MB);                    // 16 MB

  k_cast_hs<<<4096, 256, 0, stream>>>(hs, hsb, 1048576);
  k_transpose_cast<<<dim3(32, 32, 4), dim3(32, 8), 0, stream>>>(Wq, Wk, Wv, Wo, TqW, TkW, TvW, ToW);

  // Q = (hs@Wq+bq)*0.125, K = hs@Wk+bk  (rows=tokens M=4096, cols=D N=1024)
  k_gemm<0><<<dim3(8, 32), 256, 0, stream>>>(hsb, TqW, 1024, bq, nullptr, Qb, 0.125f);
  k_gemm<0><<<dim3(8, 32), 256, 0, stream>>>(hsb, TkW, 1024, bk, nullptr, Kb, 1.0f);
  // VT = (hs@Wv)^T = Wv^T @ hs^T  (rows=dims M=1024, cols=tokens N=4096)
  k_gemm<1><<<dim3(32, 8), 256, 0, stream>>>(TvW, hsb, 1024, bv, nullptr, VTb, 1.0f);

  k_attn<<<dim3(128, 16, 2), 256, 0, stream>>>(Qb, Kb, VTb, mask, probs, ctxb);

  // h = ctx@Wo + bo + hs
  k_gemm<2><<<dim3(8, 32), 256, 0, stream>>>(ctxb, ToW, 1024, bo, hs, hbuf, 1.0f);
  k_ln<<<4096, 256, 0, stream>>>(hbuf, lnw, lnb, out);
}

// Round 7
// 456.019 us; speedup vs baseline: 2.0639x; 1.2272x over previous
//
#include <hip/hip_runtime.h>
#include <stdint.h>

// Problem dims (fixed)
// B=2, S=2048, D=1024, H=16, DH=64, tokens T=4096

typedef __attribute__((ext_vector_type(8))) short short8;
typedef __attribute__((ext_vector_type(4))) float f32x4;

__device__ __forceinline__ unsigned short f2b(float f) {
  union { float f; unsigned u; } v; v.f = f;
  unsigned u = v.u;
  return (unsigned short)((u + 0x7fffu + ((u >> 16) & 1u)) >> 16);
}

__device__ __forceinline__ float b2f(unsigned short s) {
  union { unsigned u; float f; } v;
  v.u = ((unsigned)s) << 16;
  return v.f;
}

// ---------------- cast hidden_states fp32 -> bf16 ----------------
__global__ void k_cast_hs(const float* __restrict__ x, unsigned short* __restrict__ y, int n4) {
  int i = blockIdx.x * blockDim.x + threadIdx.x;
  if (i < n4) {
    float4 v = ((const float4*)x)[i];
    ushort4 o;
    o.x = f2b(v.x); o.y = f2b(v.y); o.z = f2b(v.z); o.w = f2b(v.w);
    ((ushort4*)y)[i] = o;
  }
}

// ---------------- transpose+cast the four weight matrices ----------------
__global__ void k_transpose_cast(const float* __restrict__ Wq, const float* __restrict__ Wk,
                                 const float* __restrict__ Wv, const float* __restrict__ Wo,
                                 unsigned short* __restrict__ Tq, unsigned short* __restrict__ Tk,
                                 unsigned short* __restrict__ Tv, unsigned short* __restrict__ To) {
  __shared__ float tile[32][33];
  const float* W; unsigned short* T;
  switch (blockIdx.z) {
    case 0: W = Wq; T = Tq; break;
    case 1: W = Wk; T = Tk; break;
    case 2: W = Wv; T = Tv; break;
    default: W = Wo; T = To; break;
  }
  int n0 = blockIdx.x * 32, k0 = blockIdx.y * 32;
  int tx = threadIdx.x, ty = threadIdx.y;
#pragma unroll
  for (int j = 0; j < 4; ++j)
    tile[ty + j * 8][tx] = W[(size_t)(k0 + ty + j * 8) * 1024 + n0 + tx];
  __syncthreads();
#pragma unroll
  for (int j = 0; j < 4; ++j)
    T[(size_t)(n0 + ty + j * 8) * 1024 + k0 + tx] = f2b(tile[tx][ty + j * 8]);
}

// ---------------- m97-style 128x128 bf16 MFMA GEMM, C = A @ Bt^T ----------------
// MODE 0: out bf16 [B,H,S,DH], rows=tokens, cols=D, v=(acc+bias[col])*qscale  (Q, K)
// MODE 1: out bf16 [B,H,DH,S], rows=D (dims), cols=tokens, +bias[row]  (V transposed)
// MODE 2: out fp32 h[row*1024+col] = acc + bias[col] + resid[row*1024+col]  (out proj)
template <int MODE>
__global__ __launch_bounds__(256) void k_gemm(const unsigned short* __restrict__ A,
                                              const unsigned short* __restrict__ Bt, int Kd,
                                              const float* __restrict__ bias,
                                              const float* __restrict__ resid,
                                              void* __restrict__ outp, float qscale) {
  __shared__ __align__(16) unsigned short Asm[128 * 32];
  __shared__ __align__(16) unsigned short Bsm[128 * 32];
  const int t = threadIdx.x, w = t >> 6, l = t & 63;
  const int m0 = blockIdx.y * 128, n0 = blockIdx.x * 128;
  const int wr = w >> 1, wc = w & 1;
  const int lr = l & 15, lg = l >> 4;

  f32x4 acc[4][4];
#pragma unroll
  for (int mi = 0; mi < 4; ++mi)
#pragma unroll
    for (int ni = 0; ni < 4; ++ni) acc[mi][ni] = (f32x4){0.f, 0.f, 0.f, 0.f};

  const int kcol = (l & 3) * 8;
  for (int kt = 0; kt < Kd / 32; ++kt) {
    const int k0 = kt * 32;
#pragma unroll
    for (int i = 0; i < 2; ++i) {
      int ra = (i * 4 + w) * 16 + (l >> 2);
      const unsigned short* ga = A + (size_t)(m0 + ra) * Kd + k0 + kcol;
      __builtin_amdgcn_global_load_lds((const __attribute__((address_space(1))) void*)ga,
                                       (__attribute__((address_space(3))) void*)((char*)Asm + (i * 4 + w) * 1024),
                                       16, 0, 0);
      const unsigned short* gb = Bt + (size_t)(n0 + ra) * Kd + k0 + kcol;
      __builtin_amdgcn_global_load_lds((const __attribute__((address_space(1))) void*)gb,
                                       (__attribute__((address_space(3))) void*)((char*)Bsm + (i * 4 + w) * 1024),
                                       16, 0, 0);
    }
    __syncthreads();
    short8 af[4], bfv[4];
#pragma unroll
    for (int mi = 0; mi < 4; ++mi)
      af[mi] = *(const short8*)&Asm[(wr * 64 + mi * 16 + lr) * 32 + lg * 8];
#pragma unroll
    for (int ni = 0; ni < 4; ++ni)
      bfv[ni] = *(const short8*)&Bsm[(wc * 64 + ni * 16 + lr) * 32 + lg * 8];
#pragma unroll
    for (int mi = 0; mi < 4; ++mi)
#pragma unroll
      for (int ni = 0; ni < 4; ++ni)
        acc[mi][ni] = __builtin_amdgcn_mfma_f32_16x16x32_bf16(af[mi], bfv[ni], acc[mi][ni], 0, 0, 0);
    __syncthreads();
  }

#pragma unroll
  for (int mi = 0; mi < 4; ++mi) {
#pragma unroll
    for (int ni = 0; ni < 4; ++ni) {
#pragma unroll
      for (int r = 0; r < 4; ++r) {
        int row = m0 + wr * 64 + mi * 16 + lg * 4 + r;
        int col = n0 + wc * 64 + ni * 16 + lr;
        float v = acc[mi][ni][r];
        if constexpr (MODE == 0) {
          v = (v + bias[col]) * qscale;
          int b = row >> 11, s = row & 2047, h = col >> 6, dh = col & 63;
          ((unsigned short*)outp)[((size_t)((b * 16 + h) * 2048 + s)) * 64 + dh] = f2b(v);
        } else if constexpr (MODE == 1) {
          v += bias[row];
          int h = row >> 6, dh = row & 63, b = col >> 11, s = col & 2047;
          ((unsigned short*)outp)[((size_t)((b * 16 + h) * 64 + dh)) * 2048 + s] = f2b(v);
        } else {
          v += bias[col] + resid[(size_t)row * 1024 + col];
          ((float*)outp)[(size_t)row * 1024 + col] = v;
        }
      }
    }
  }
}

// ---------------- fused attention: scores + softmax + probs write + PV ----------------
// grid (S/16, H, B), block 256 (4 waves). Wave w owns score cols [w*512, w*512+512).
// SWAPPED QK^T: mfma(K,Q) -> lane holds one q-row (q = lane&15), k in regs.
// P staged in LDS as bf16 [16][2048]; probs drained with single-row 2KB-contiguous
// nontemporal stores (fixes L2 bank hotspot of 8KB-strided multi-row stores).
// NOTE: every loop touching sc[] MUST be fully unrolled (rule #20).
__global__ __launch_bounds__(256, 2) void k_attn(const unsigned short* __restrict__ Q,
                                                 const unsigned short* __restrict__ K,
                                                 const unsigned short* __restrict__ VT,
                                                 const float* __restrict__ mask,
                                                 float* __restrict__ probs,
                                                 unsigned short* __restrict__ ctx) {
  __shared__ float smax[4][16];
  __shared__ float ssum[4][16];
  // Pall: full P tile in bf16, row stride 2056 (pad 16B -> 2-way bank alias only).
  // redbuf (16KB) overlays Pall after drain+PV are done (barrier-separated).
  __shared__ __align__(16) unsigned short Pall[16][2056];
  float (*redbuf)[16][64] = (float(*)[16][64])Pall;

  const int t = threadIdx.x, w = t >> 6, l = t & 63;
  const int qb = blockIdx.x, h = blockIdx.y, b = blockIdx.z;
  const int q0 = qb * 16;
  const int lr = l & 15, lg = l >> 4;
  const size_t head = ((size_t)(b * 16 + h)) * 2048 * 64;
  const unsigned short* Qh = Q + head + (size_t)q0 * 64;
  const unsigned short* Kh = K + head;
  const unsigned short* VTh = VT + head;

  // Q fragment as B-operand: col=lr -> q row, k = lg*8+j
  short8 aq0 = *(const short8*)(Qh + lr * 64 + lg * 8);
  short8 aq1 = *(const short8*)(Qh + lr * 64 + 32 + lg * 8);

  f32x4 sc[32];
#pragma unroll
  for (int ni = 0; ni < 32; ++ni) {
    int col = w * 512 + ni * 16 + lr;  // K row (A-operand row index)
    short8 bk0 = *(const short8*)(Kh + (size_t)col * 64 + lg * 8);
    short8 bk1 = *(const short8*)(Kh + (size_t)col * 64 + 32 + lg * 8);
    f32x4 c = (f32x4){0.f, 0.f, 0.f, 0.f};
    c = __builtin_amdgcn_mfma_f32_16x16x32_bf16(bk0, aq0, c, 0, 0, 0);  // A=K, B=Q
    c = __builtin_amdgcn_mfma_f32_16x16x32_bf16(bk1, aq1, c, 0, 0, 0);
    // lane holds S[k = w*512+ni*16+lg*4+r][q = lr]; scale already folded into Q
    f32x4 mv = *(const f32x4*)(mask + b * 2048 + w * 512 + ni * 16 + lg * 4);
    sc[ni] = c + mv;
  }

  // ---- softmax: row q=lr is lane-local ----
  float vmax = -1e30f;
#pragma unroll
  for (int ni = 0; ni < 32; ++ni)
#pragma unroll
    for (int r = 0; r < 4; ++r) vmax = fmaxf(vmax, sc[ni][r]);
  vmax = fmaxf(vmax, __shfl_xor(vmax, 16));
  vmax = fmaxf(vmax, __shfl_xor(vmax, 32));
  if (l < 16) smax[w][l] = vmax;
  __syncthreads();
  float m = fmaxf(fmaxf(smax[0][lr], smax[1][lr]), fmaxf(smax[2][lr], smax[3][lr]));

  float vsum = 0.f;
#pragma unroll
  for (int ni = 0; ni < 32; ++ni)
#pragma unroll
    for (int r = 0; r < 4; ++r) {
      float p = __expf(sc[ni][r] - m);
      sc[ni][r] = p;
      vsum += p;
    }
  vsum += __shfl_xor(vsum, 16);
  vsum += __shfl_xor(vsum, 32);
  if (l < 16) ssum[w][l] = vsum;
  __syncthreads();
  float rinv = 1.f / (ssum[0][lr] + ssum[1][lr] + ssum[2][lr] + ssum[3][lr]);

  // ---- stage normalized P (bf16) into Pall[q][k]: wave w fills cols [w*512,+512) ----
#pragma unroll
  for (int ni = 0; ni < 32; ++ni) {
    float p0 = sc[ni][0] * rinv, p1 = sc[ni][1] * rinv;
    float p2 = sc[ni][2] * rinv, p3 = sc[ni][3] * rinv;
    ushort4 pk;
    pk.x = f2b(p0); pk.y = f2b(p1); pk.z = f2b(p2); pk.w = f2b(p3);
    *(ushort4*)&Pall[lr][w * 512 + ni * 16 + lg * 4] = pk;
  }
  __syncthreads();

  // ---- PV: ctx[16 x 64], K-dim split across waves (wave w reads its own chunk) ----
  f32x4 cacc[4];
#pragma unroll
  for (int n = 0; n < 4; ++n) cacc[n] = (f32x4){0.f, 0.f, 0.f, 0.f};

#pragma unroll
  for (int kc = 0; kc < 16; ++kc) {
    short8 pa = *(const short8*)&Pall[lr][w * 512 + kc * 32 + lg * 8];
    size_t kg = (size_t)w * 512 + kc * 32;
#pragma unroll
    for (int n = 0; n < 4; ++n) {
      short8 bv = *(const short8*)(VTh + (size_t)(n * 16 + lr) * 2048 + kg + lg * 8);
      cacc[n] = __builtin_amdgcn_mfma_f32_16x16x32_bf16(pa, bv, cacc[n], 0, 0, 0);
    }
  }

  // ---- probs drain: wave w -> rows w*4..w*4+3; 2KB-contiguous nontemporal stores ----
  {
    const size_t prow0 = ((size_t)((b * 16 + h) * 2048 + q0)) * 2048;
#pragma unroll
    for (int rr = 0; rr < 4; ++rr) {
      int row = w * 4 + rr;
      float* gp = probs + prow0 + (size_t)row * 2048;
#pragma unroll
      for (int p = 0; p < 4; ++p) {
        short8 pv = *(const short8*)&Pall[row][p * 512 + l * 8];
        f32x4 o0, o1;
        o0[0] = b2f((unsigned short)pv[0]); o0[1] = b2f((unsigned short)pv[1]);
        o0[2] = b2f((unsigned short)pv[2]); o0[3] = b2f((unsigned short)pv[3]);
        o1[0] = b2f((unsigned short)pv[4]); o1[1] = b2f((unsigned short)pv[5]);
        o1[2] = b2f((unsigned short)pv[6]); o1[3] = b2f((unsigned short)pv[7]);
        f32x4* dst = (f32x4*)(gp + p * 512 + l * 8);
        __builtin_nontemporal_store(o0, dst);
        __builtin_nontemporal_store(o1, dst + 1);
      }
    }
  }
  __syncthreads();  // drain+PV reads of Pall done -> redbuf may overlay

  // cross-wave reduce of ctx partials
#pragma unroll
  for (int n = 0; n < 4; ++n)
#pragma unroll
    for (int r = 0; r < 4; ++r)
      redbuf[w][lg * 4 + r][n * 16 + lr] = cacc[n][r];
  __syncthreads();

  {
    int row = t >> 4;          // 0..15
    int c0 = (t & 15) * 4;     // 0..60
    float v0 = redbuf[0][row][c0] + redbuf[1][row][c0] + redbuf[2][row][c0] + redbuf[3][row][c0];
    float v1 = redbuf[0][row][c0 + 1] + redbuf[1][row][c0 + 1] + redbuf[2][row][c0 + 1] + redbuf[3][row][c0 + 1];
    float v2 = redbuf[0][row][c0 + 2] + redbuf[1][row][c0 + 2] + redbuf[2][row][c0 + 2] + redbuf[3][row][c0 + 2];
    float v3 = redbuf[0][row][c0 + 3] + redbuf[1][row][c0 + 3] + redbuf[2][row][c0 + 3] + redbuf[3][row][c0 + 3];
    ushort4 o;
    o.x = f2b(v0); o.y = f2b(v1); o.z = f2b(v2); o.w = f2b(v3);
    *(ushort4*)(ctx + ((size_t)(b * 2048 + q0 + row)) * 1024 + h * 64 + c0) = o;
  }
}

// ---------------- LayerNorm over D=1024 per token ----------------
__global__ __launch_bounds__(256) void k_ln(const float* __restrict__ hbuf, const float* __restrict__ g,
                                            const float* __restrict__ be, float* __restrict__ out) {
  __shared__ float psum[4];
  __shared__ float psq[4];
  int tok = blockIdx.x;
  int t = threadIdx.x, w = t >> 6;
  float4 v = ((const float4*)(hbuf + (size_t)tok * 1024))[t];
  float s = v.x + v.y + v.z + v.w;
  float q = v.x * v.x + v.y * v.y + v.z * v.z + v.w * v.w;
#pragma unroll
  for (int off = 32; off >= 1; off >>= 1) {
    s += __shfl_xor(s, off);
    q += __shfl_xor(q, off);
  }
  if ((t & 63) == 0) { psum[w] = s; psq[w] = q; }
  __syncthreads();
  float S = psum[0] + psum[1] + psum[2] + psum[3];
  float Qs = psq[0] + psq[1] + psq[2] + psq[3];
  float u = S * (1.f / 1024.f);
  float var = Qs * (1.f / 1024.f) - u * u;
  float rstd = rsqrtf(var + 1e-12f);
  float4 gv = ((const float4*)g)[t];
  float4 bv = ((const float4*)be)[t];
  float4 o;
  o.x = gv.x * ((v.x - u) * rstd) + bv.x;
  o.y = gv.y * ((v.y - u) * rstd) + bv.y;
  o.z = gv.z * ((v.z - u) * rstd) + bv.z;
  o.w = gv.w * ((v.w - u) * rstd) + bv.w;
  ((float4*)(out + (size_t)tok * 1024))[t] = o;
}

extern "C" void kernel_launch(void* const* d_in, const int* in_sizes, int n_in,
                              void* d_out, int out_size, void* d_ws, size_t ws_size,
                              hipStream_t stream) {
  const float* hs   = (const float*)d_in[0];
  const float* mask = (const float*)d_in[1];
  const float* Wq   = (const float*)d_in[2];
  const float* bq   = (const float*)d_in[3];
  const float* Wk   = (const float*)d_in[4];
  const float* bk   = (const float*)d_in[5];
  const float* Wv   = (const float*)d_in[6];
  const float* bv   = (const float*)d_in[7];
  const float* Wo   = (const float*)d_in[8];
  const float* bo   = (const float*)d_in[9];
  const float* lnw  = (const float*)d_in[10];
  const float* lnb  = (const float*)d_in[11];

  float* out = (float*)d_out;
  float* probs = out + (size_t)4194304;  // B*S*D = 2*2048*1024

  char* ws = (char*)d_ws;
  const size_t MB = 1u << 20;
  unsigned short* hsb = (unsigned short*)(ws + 0 * MB);    // 8 MB
  unsigned short* TqW = (unsigned short*)(ws + 8 * MB);    // 2 MB each
  unsigned short* TkW = (unsigned short*)(ws + 10 * MB);
  unsigned short* TvW = (unsigned short*)(ws + 12 * MB);
  unsigned short* ToW = (unsigned short*)(ws + 14 * MB);
  unsigned short* Qb  = (unsigned short*)(ws + 16 * MB);   // 8 MB
  unsigned short* Kb  = (unsigned short*)(ws + 24 * MB);   // 8 MB
  unsigned short* VTb = (unsigned short*)(ws + 32 * MB);   // 8 MB
  unsigned short* ctxb = (unsigned short*)(ws + 40 * MB);  // 8 MB
  float* hbuf = (float*)(ws + 48 * MB);                    // 16 MB

  k_cast_hs<<<4096, 256, 0, stream>>>(hs, hsb, 1048576);
  k_transpose_cast<<<dim3(32, 32, 4), dim3(32, 8), 0, stream>>>(Wq, Wk, Wv, Wo, TqW, TkW, TvW, ToW);

  // Q = (hs@Wq+bq)*0.125, K = hs@Wk+bk  (rows=tokens M=4096, cols=D N=1024)
  k_gemm<0><<<dim3(8, 32), 256, 0, stream>>>(hsb, TqW, 1024, bq, nullptr, Qb, 0.125f);
  k_gemm<0><<<dim3(8, 32), 256, 0, stream>>>(hsb, TkW, 1024, bk, nullptr, Kb, 1.0f);
  // VT = (hs@Wv)^T = Wv^T @ hs^T  (rows=dims M=1024, cols=tokens N=4096)
  k_gemm<1><<<dim3(32, 8), 256, 0, stream>>>(TvW, hsb, 1024, bv, nullptr, VTb, 1.0f);

  k_attn<<<dim3(128, 16, 2), 256, 0, stream>>>(Qb, Kb, VTb, mask, probs, ctxb);

  // h = ctx@Wo + bo + hs
  k_gemm<2><<<dim3(8, 32), 256, 0, stream>>>(ctxb, ToW, 1024, bo, hs, hbuf, 1.0f);
  k_ln<<<4096, 256, 0, stream>>>(hbuf, lnw, lnb, out);
}